// Round 15
// baseline (90.468 us; speedup 1.0000x reference)
//
#include <hip/hip_runtime.h>
#include <math.h>

// Problem constants (match reference)
#define T_ 16
#define C_ 4
#define S_ 256
static constexpr float DT      = 0.05f;
static constexpr float JITTER  = 1e-5f;
static constexpr float CLIPV   = 1e4f;

typedef float f32x4 __attribute__((ext_vector_type(4)));

// Output layout (floats, concatenated in return order)
static constexpr int TR_SIZE     = T_ * (C_ * S_) * (C_ * S_);   // 16,777,216
static constexpr int DRIFT_OFF   = TR_SIZE;                       // [T,C,C,2] = 512
static constexpr int DISP_OFF    = DRIFT_OFF + T_ * C_ * C_ * 2;  // [T,C,C,2,2] = 1024
static constexpr int SCALES_OFF  = DISP_OFF + T_ * C_ * C_ * 4;   // [C,C] = 16
static constexpr int MIX_OFF     = SCALES_OFF + C_ * C_;          // 1

// ws layout: per (t,i,j) block record of 8 floats:
//   [0]=inv00 [1]=inv01 [2]=inv11 [3]=h(=-0.5*logdet) [4]=drift_x [5]=drift_y [6]=scale
// ws[2048] = mix
static constexpr int WS_REC = 8;
static constexpr int WS_MIX = T_ * C_ * C_ * WS_REC;  // 2048

__device__ __forceinline__ float sanv(float x) {
    if (isnan(x)) return 0.f;
    return fminf(fmaxf(x, -CLIPV), CLIPV);
}

// ---------------- Kernel 1: per-(t,i,j) block prep (1 block, 256 threads) ---
__global__ __launch_bounds__(256)
void prep_kernel(const float* __restrict__ means,
                 const float* __restrict__ covs,
                 const float* __restrict__ bsr,
                 const float* __restrict__ mixlogit,
                 float* __restrict__ out,
                 float* __restrict__ ws) {
    int tid = threadIdx.x;
    if (tid >= T_ * C_ * C_) return;
    int t = tid >> 4;
    int i = (tid >> 2) & 3;
    int j = tid & 3;
    int bl = tid;  // (t*4+i)*4+j

    // sanitized means
    float mix_ = sanv(means[(t * C_ + i) * 2 + 0]);
    float miy  = sanv(means[(t * C_ + i) * 2 + 1]);
    float mjx  = sanv(means[(t * C_ + j) * 2 + 0]);
    float mjy  = sanv(means[(t * C_ + j) * 2 + 1]);
    float dx = sanv(DT * (mix_ - mjx));
    float dy = sanv(DT * (miy - mjy));
    out[DRIFT_OFF + bl * 2 + 0] = dx;
    out[DRIFT_OFF + bl * 2 + 1] = dy;

    // sanitized+symmetrized covariances
    const float* ci = covs + (t * C_ + i) * 4;
    const float* cj = covs + (t * C_ + j) * 4;
    float ci00 = sanv(ci[0]), ci01 = 0.5f * (sanv(ci[1]) + sanv(ci[2])), ci11 = sanv(ci[3]);
    float cj00 = sanv(cj[0]), cj01 = 0.5f * (sanv(cj[1]) + sanv(cj[2])), cj11 = sanv(cj[3]);

    // disp = I + 2*DT^2*(ci+cj), then san_m(disp + JITTER*I)
    const float k2 = 2.0f * DT * DT;  // 0.005
    float a = sanv(1.0f + k2 * (ci00 + cj00) + JITTER);
    float b = sanv(        k2 * (ci01 + cj01));
    float c = sanv(1.0f + k2 * (ci11 + cj11) + JITTER);

    // _stable_inv_logdet
    float ds = fmaxf(0.5f * (fabsf(a) + fabsf(c)), 1.0f);
    float ra = 0.f, rb = 0.f, rc = 0.f, det0 = 1.f;
    bool found = false;
    float jit = 1e-5f;  // j0 = max(JITTER, 1e-6)
    #pragma unroll
    for (int k = 0; k < 8; ++k) {
        float ja = sanv(a + jit * ds);
        float jb = sanv(b);
        float jc = sanv(c + jit * ds);
        float det = ja * jc - jb * jb;
        if (!found && ja > 0.f && det > 0.f) {
            found = true; ra = ja; rb = jb; rc = jc; det0 = det;
        }
        jit *= 10.f;
    }

    float i00, i01, i11, ld, o00, o01, o11;
    if (found) {
        i00 = sanv(rc / det0);
        i01 = sanv(-rb / det0);
        i11 = sanv(ra / det0);
        ld = logf(det0);
        if (isnan(ld)) ld = 0.f;
        else if (isinf(ld)) ld = (ld > 0.f) ? 20.f : -20.f;
        o00 = ra; o01 = rb; o11 = rc;
    } else {
        float jf = 1e3f;  // j0 * 10^8
        float sd0 = fmaxf(fabsf(a), jf * ds + 1e-4f);
        float sd1 = fmaxf(fabsf(c), jf * ds + 1e-4f);
        o00 = sanv(sd0 + jf * ds); o11 = sanv(sd1 + jf * ds); o01 = 0.f;
        float dg0 = fmaxf(o00, 1e-6f), dg1 = fmaxf(o11, 1e-6f);
        i00 = sanv(1.f / dg0); i11 = sanv(1.f / dg1); i01 = 0.f;
        ld = logf(dg0) + logf(dg1);
        if (isnan(ld)) ld = 0.f;
        else if (isinf(ld)) ld = (ld > 0.f) ? 20.f : -20.f;
    }
    out[DISP_OFF + bl * 4 + 0] = o00;
    out[DISP_OFF + bl * 4 + 1] = o01;
    out[DISP_OFF + bl * 4 + 2] = o01;
    out[DISP_OFF + bl * 4 + 3] = o11;

    // scales: softplus(bsr) + 0.01  (stable: max(x,0)+log1p(exp(-|x|)))
    float x = bsr[i * 4 + j];
    float sc = fmaxf(x, 0.f) + log1pf(expf(-fabsf(x))) + 0.01f;
    if (t == 0) out[SCALES_OFF + i * 4 + j] = sc;

    float* w = ws + bl * WS_REC;
    w[0] = i00; w[1] = i01; w[2] = i11; w[3] = -0.5f * ld;  // h = -0.5*logdet
    w[4] = dx;  w[5] = dy;  w[6] = sc;  w[7] = 0.f;

    if (tid == 0) {
        float lg = mixlogit[0];
        float mx = 1.f / (1.f + expf(-lg));
        out[MIX_OFF] = mx;
        ws[WS_MIX]   = mx;
    }
}

// ---------------- Kernel 2: ONE WAVE PER ROW (no LDS, no barrier) ----------
// Row r = blockIdx.x*4 + wave = (t, i, a). Each lane covers 16 columns:
// for store k (=j-block, 0..3), lane l writes columns k*256 + 4l .. 4l+3
// -> 1 KB contiguous per store instruction, ws record wave-uniform per k,
// site pairs loaded once per lane and reused across all 4 k.
// Row sum via 6-step __shfl_xor butterfly (all lanes get s1).
// Stores are PLAIN (not nontemporal): the 67 MB output fits in the 256 MB
// Infinity Cache, so write-back caching lets stores complete at cache speed
// and the HBM drain overlaps post-kernel work (r13 post-mortem: nt stores
// pinned the kernel at 3.2 TB/s vs the 6 TB/s fill).
__global__ __launch_bounds__(256)
void row_kernel(const float* __restrict__ site,
                const float* __restrict__ ws,
                float* __restrict__ tr) {
    int tid  = threadIdx.x;
    int lane = tid & 63;
    int r = __builtin_amdgcn_readfirstlane((blockIdx.x << 2) | (tid >> 6));
    int t = r >> 10;
    int i = (r >> 8) & 3;
    int a = r & 255;

    // lane's 4 sites: b = 4*lane .. 4*lane+3 (128 f32x4 total; max idx 127)
    const f32x4* s4 = (const f32x4*)site;
    f32x4 p0 = s4[2 * lane];
    f32x4 p1 = s4[2 * lane + 1];
    float2 sa = ((const float2*)site)[a];        // wave-uniform
    float mx = ws[WS_MIX];

    float bx[4] = {p0.x, p0.z, p1.x, p1.z};
    float by[4] = {p0.y, p0.w, p1.y, p1.w};

    float v[4][4];
    float local = 0.f;
    #pragma unroll
    for (int k = 0; k < 4; ++k) {                // k = j-block, wave-uniform record
        const float* w = ws + ((t * C_ + i) * C_ + k) * WS_REC;
        float i00 = w[0], i01 = w[1], i11 = w[2], h = w[3];
        float dx = w[4],  dy = w[5],  sc = w[6];
        float ox = sa.x - dx, oy = sa.y - dy;
        #pragma unroll
        for (int s = 0; s < 4; ++s) {
            float cx = ox - bx[s], cy = oy - by[s];
            float u = i00 * cx + i01 * cy;
            float z = i01 * cx + i11 * cy;
            float q = cx * u + cy * z;
            q = fminf(fmaxf(q, 0.f), 60.f);                 // binding clip: keep
            float e = fminf(fmaxf(h - q, -60.f), 20.f);     // binding clip: keep
            float val = sc * __expf(e);
            v[k][s] = val;
            local += val;
        }
    }

    // 64-lane butterfly all-reduce (no LDS, no barrier)
    #pragma unroll
    for (int m = 1; m < 64; m <<= 1) local += __shfl_xor(local, m, 64);
    float s1 = local;

    // uniform epilogue with v_rcp_f32 (rel err ~1e-7 << absmax headroom)
    float d1 = fmaxf(s1, JITTER);
    float r1 = __builtin_amdgcn_rcpf(d1);
    float s2 = s1 * r1;
    float d2 = fmaxf(s2, JITTER);
    float r2 = __builtin_amdgcn_rcpf(d2);
    float sum_t2 = s2 * r2;
    float omx = 1.f - mx;
    float s3 = omx * sum_t2 + mx;
    float d3 = fmaxf(s3, JITTER);
    float r3 = __builtin_amdgcn_rcpf(d3);
    float scale = omx * r1 * r2 * r3;
    float diag  = mx * r3;

    size_t base = ((size_t)t << 20) + (size_t)(i * S_ + a) * 1024;
    f32x4* dst = (f32x4*)(tr + base);
    #pragma unroll
    for (int k = 0; k < 4; ++k) {
        f32x4 o;
        o.x = v[k][0] * scale; o.y = v[k][1] * scale;
        o.z = v[k][2] * scale; o.w = v[k][3] * scale;
        // diagonal of the (i,i) block: k==i, lane a>>2, slot a&3
        if (k == i && lane == (a >> 2)) {
            int sl = a & 3;
            if      (sl == 0) o.x += diag;
            else if (sl == 1) o.y += diag;
            else if (sl == 2) o.z += diag;
            else              o.w += diag;
        }
        dst[(k << 6) + lane] = o;   // plain store: write-back via L2/LLC
    }
}

extern "C" void kernel_launch(void* const* d_in, const int* in_sizes, int n_in,
                              void* d_out, int out_size, void* d_ws, size_t ws_size,
                              hipStream_t stream) {
    const float* means    = (const float*)d_in[0];
    const float* covs     = (const float*)d_in[1];
    const float* site     = (const float*)d_in[2];
    const float* bsr      = (const float*)d_in[3];
    const float* mixlogit = (const float*)d_in[4];
    float* out = (float*)d_out;
    float* ws  = (float*)d_ws;

    prep_kernel<<<1, 256, 0, stream>>>(means, covs, bsr, mixlogit, out, ws);
    row_kernel<<<(T_ * C_ * S_) / 4, 256, 0, stream>>>(site, ws, out);
}